// Round 11
// baseline (341.880 us; speedup 1.0000x reference)
//
#include <hip/hip_runtime.h>
#include <hip/hip_bf16.h>
#include <math.h>

#define B_  4
#define T_  2048
#define D_  1024
#define H_  16
#define HD_ 64
#define M_  8192   // B_*T_

typedef __attribute__((ext_vector_type(8))) short bf16x8;
typedef __attribute__((ext_vector_type(4))) float f32x4;

static __device__ __forceinline__ unsigned short f2bf(float f){
    unsigned int u = __float_as_uint(f);
    unsigned int r = u + 0x7FFFu + ((u >> 16) & 1u);   // RNE
    return (unsigned short)(r >> 16);
}
static __device__ __forceinline__ float bfbits2f(unsigned short s){
    return __uint_as_float(((unsigned int)s) << 16);
}
static __device__ __forceinline__ void gload_lds16(const void* g, void* l){
    __builtin_amdgcn_global_load_lds(
        (const __attribute__((address_space(1))) unsigned int*)g,
        (__attribute__((address_space(3))) unsigned int*)l, 16, 0, 0);
}

union U16x16 { unsigned short us[16]; uint4 q[2]; };

// ---------------------------------------------------------------------------
// prep_x2: x fp32 -> xh (bf16 hi) + xl (bf16 residual). 16 el/thread.
// ---------------------------------------------------------------------------
__global__ __launch_bounds__(256) void prep_x2(
    const float* __restrict__ x,
    unsigned short* __restrict__ xh, unsigned short* __restrict__ xl)
{
    const size_t i = ((size_t)blockIdx.x*256 + threadIdx.x)*16;
    U16x16 uh, ul;
#pragma unroll
    for (int j=0;j<16;j+=4){
        float4 f = *(const float4*)(x+i+j);
        float v[4] = {f.x,f.y,f.z,f.w};
#pragma unroll
        for (int k=0;k<4;k++){
            unsigned short hb = f2bf(v[k]);
            uh.us[j+k] = hb;
            ul.us[j+k] = f2bf(v[k] - bfbits2f(hb));
        }
    }
    *(uint4*)(xh+i)   = uh.q[0]; *(uint4*)(xh+i+8) = uh.q[1];
    *(uint4*)(xl+i)   = ul.q[0]; *(uint4*)(xl+i+8) = ul.q[1];
}

// ---------------------------------------------------------------------------
// prep_wqkv2: W{q,k,v}[16][1024][64] -> wt_hi/wt_lo[3072][1024] (operand-major).
// ---------------------------------------------------------------------------
__global__ __launch_bounds__(256) void prep_wqkv2(
    const float* __restrict__ Wq, const float* __restrict__ Wk,
    const float* __restrict__ Wv,
    unsigned short* __restrict__ wh, unsigned short* __restrict__ wl)
{
    const int dt = blockIdx.x;
    const int zh = blockIdx.y;
    const int z = zh >> 4, h = zh & 15;
    const float* src = ((z==0)?Wq:(z==1)?Wk:Wv) + (size_t)h*1024*64;
    __shared__ float Tt[64][68];
    const int t = threadIdx.x;
    const int r = t >> 2, c4 = (t & 3) * 16;
    const float* sp = src + (size_t)(dt*64 + r)*64 + c4;
    float4 v0=*(const float4*)(sp+0), v1=*(const float4*)(sp+4);
    float4 v2=*(const float4*)(sp+8), v3=*(const float4*)(sp+12);
    *(float4*)&Tt[r][c4+ 0]=v0; *(float4*)&Tt[r][c4+ 4]=v1;
    *(float4*)&Tt[r][c4+ 8]=v2; *(float4*)&Tt[r][c4+12]=v3;
    __syncthreads();
    const int er = t >> 2, dk = (t & 3) * 16;
    U16x16 uh, ul;
#pragma unroll
    for (int j=0;j<16;j++){
        float v = Tt[dk+j][er];
        unsigned short hb = f2bf(v);
        uh.us[j] = hb;
        ul.us[j] = f2bf(v - bfbits2f(hb));
    }
    size_t off = (size_t)(z*1024 + h*64 + er)*1024 + dt*64 + dk;
    *(uint4*)(wh+off)   = uh.q[0]; *(uint4*)(wh+off+8) = uh.q[1];
    *(uint4*)(wl+off)   = ul.q[0]; *(uint4*)(wl+off+8) = ul.q[1];
}

// ---------------------------------------------------------------------------
// prep_wo: Wo[1024][1024] -> wot[n][k] bf16 (hi only).
// ---------------------------------------------------------------------------
__global__ __launch_bounds__(256) void prep_wo(
    const float* __restrict__ Wo, unsigned short* __restrict__ wot)
{
    const int kt = blockIdx.x, nt = blockIdx.y;
    __shared__ float Tt[64][68];
    const int t = threadIdx.x;
    const int r = t >> 2, c4 = (t & 3) * 16;
    const float* sp = Wo + (size_t)(kt*64 + r)*1024 + nt*64 + c4;
    float4 v0=*(const float4*)(sp+0), v1=*(const float4*)(sp+4);
    float4 v2=*(const float4*)(sp+8), v3=*(const float4*)(sp+12);
    *(float4*)&Tt[r][c4+ 0]=v0; *(float4*)&Tt[r][c4+ 4]=v1;
    *(float4*)&Tt[r][c4+ 8]=v2; *(float4*)&Tt[r][c4+12]=v3;
    __syncthreads();
    const int er = t >> 2, dk = (t & 3) * 16;
    U16x16 u;
#pragma unroll
    for (int j=0;j<16;j++) u.us[j] = f2bf(Tt[dk+j][er]);
    unsigned short* dst = wot + (size_t)(nt*64 + er)*1024 + kt*64 + dk;
    *(uint4*)(dst)   = u.q[0];
    *(uint4*)(dst+8) = u.q[1];
}

// ---------------------------------------------------------------------------
// gemm_qkv3: C[128x128]/block, 4 waves, 64x64/wave, bf16 16x16x32 MFMA.
// 2-phase double-buffered: STAGE(t+1) issued before COMPUTE(t); one barrier
// per K-tile. global_load_lds(16B) + chunk-XOR swizzle via pre-swizzled src.
// Split-precision (hi*hi+hi*lo+lo*hi) for q,k (n0<2048). Epilogue: LDS
// transpose -> contiguous 128B row stores (q/k [t][e], v [bh][d][t]).
// ---------------------------------------------------------------------------
__global__ __launch_bounds__(256) void gemm_qkv3(
    const unsigned short* __restrict__ xh, const unsigned short* __restrict__ xl,
    const unsigned short* __restrict__ wh, const unsigned short* __restrict__ wl,
    const float* __restrict__ bqv, const float* __restrict__ bkv,
    const float* __restrict__ bvv,
    unsigned short* __restrict__ qhp, unsigned short* __restrict__ qlp,
    unsigned short* __restrict__ khp, unsigned short* __restrict__ klp,
    unsigned short* __restrict__ vtp)
{
    const int m0 = blockIdx.x * 128;
    const int n0 = blockIdx.y * 128;
    const bool precise = (n0 < 2048);
    const int tid = threadIdx.x;
    const int lane = tid & 63, w = tid >> 6;
    const int wr = w >> 1, wc = w & 1;
    const int fla = lane & 15, flb = lane >> 4;

    __shared__ unsigned short Ah0[4096], Ah1[4096];
    __shared__ unsigned short Bh0[4096], Bh1[4096];
    __shared__ unsigned short Al0[4096], Al1[4096];
    __shared__ unsigned short Bl0[4096], Bl1[4096];

    f32x4 acc[4][4];
#pragma unroll
    for (int i=0;i<4;i++)
#pragma unroll
        for (int j=0;j<4;j++) acc[i][j] = (f32x4){0.f,0.f,0.f,0.f};

    const int srow0 = w*32 + (lane>>2);
    const int srow1 = srow0 + 16;
    const int spc   = lane & 3;
    const size_t ga0 = (size_t)(m0+srow0)*1024 + (size_t)((spc ^ ((srow0>>1)&3))*8);
    const size_t ga1 = (size_t)(m0+srow1)*1024 + (size_t)((spc ^ ((srow1>>1)&3))*8);
    const size_t gb0 = (size_t)(n0+srow0)*1024 + (size_t)((spc ^ ((srow0>>1)&3))*8);
    const size_t gb1 = (size_t)(n0+srow1)*1024 + (size_t)((spc ^ ((srow1>>1)&3))*8);
    const int ldso0 = w*1024;          // shorts
    const int ldso1 = w*1024 + 512;
    const int pchunk = (flb ^ ((fla>>1)&3)) * 8;

#define STAGE_Q(AH,BH,AL,BL,KS) do{ const size_t k0_ = (size_t)(KS)*32;          \
    gload_lds16(xh + ga0 + k0_, (AH) + ldso0);                                    \
    gload_lds16(xh + ga1 + k0_, (AH) + ldso1);                                    \
    gload_lds16(wh + gb0 + k0_, (BH) + ldso0);                                    \
    gload_lds16(wh + gb1 + k0_, (BH) + ldso1);                                    \
    if (precise){                                                                 \
        gload_lds16(xl + ga0 + k0_, (AL) + ldso0);                                \
        gload_lds16(xl + ga1 + k0_, (AL) + ldso1);                                \
        gload_lds16(wl + gb0 + k0_, (BL) + ldso0);                                \
        gload_lds16(wl + gb1 + k0_, (BL) + ldso1);                                \
    } }while(0)

#define COMPUTE_Q(AH,BH,AL,BL) do{                                                \
    bf16x8 afh[4], bfh[4];                                                        \
    _Pragma("unroll")                                                             \
    for (int mf=0; mf<4; ++mf)                                                    \
        afh[mf] = *(const bf16x8*)&(AH)[(wr*64+mf*16+fla)*32 + pchunk];           \
    _Pragma("unroll")                                                             \
    for (int nf=0; nf<4; ++nf)                                                    \
        bfh[nf] = *(const bf16x8*)&(BH)[(wc*64+nf*16+fla)*32 + pchunk];           \
    if (precise){                                                                 \
        bf16x8 afl[4], bfl[4];                                                    \
        _Pragma("unroll")                                                         \
        for (int mf=0; mf<4; ++mf)                                                \
            afl[mf] = *(const bf16x8*)&(AL)[(wr*64+mf*16+fla)*32 + pchunk];       \
        _Pragma("unroll")                                                         \
        for (int nf=0; nf<4; ++nf)                                                \
            bfl[nf] = *(const bf16x8*)&(BL)[(wc*64+nf*16+fla)*32 + pchunk];       \
        _Pragma("unroll")                                                         \
        for (int mf=0; mf<4; ++mf)                                                \
            _Pragma("unroll")                                                     \
            for (int nf=0; nf<4; ++nf){                                           \
                acc[mf][nf] = __builtin_amdgcn_mfma_f32_16x16x32_bf16(            \
                                  afh[mf], bfl[nf], acc[mf][nf], 0, 0, 0);        \
                acc[mf][nf] = __builtin_amdgcn_mfma_f32_16x16x32_bf16(            \
                                  afl[mf], bfh[nf], acc[mf][nf], 0, 0, 0);        \
                acc[mf][nf] = __builtin_amdgcn_mfma_f32_16x16x32_bf16(            \
                                  afh[mf], bfh[nf], acc[mf][nf], 0, 0, 0);        \
            }                                                                     \
    } else {                                                                      \
        _Pragma("unroll")                                                         \
        for (int mf=0; mf<4; ++mf)                                                \
            _Pragma("unroll")                                                     \
            for (int nf=0; nf<4; ++nf)                                            \
                acc[mf][nf] = __builtin_amdgcn_mfma_f32_16x16x32_bf16(            \
                                  afh[mf], bfh[nf], acc[mf][nf], 0, 0, 0);        \
    } }while(0)

    STAGE_Q(Ah0,Bh0,Al0,Bl0, 0);
    __syncthreads();                      // tile0 landed (vmcnt0 at barrier)
    for (int ks = 0; ks < 32; ks += 2){
        STAGE_Q(Ah1,Bh1,Al1,Bl1, ks+1);   // in flight under compute
        COMPUTE_Q(Ah0,Bh0,Al0,Bl0);
        __syncthreads();                  // tile ks+1 landed; buf0 reads done
        if (ks+2 < 32) STAGE_Q(Ah0,Bh0,Al0,Bl0, ks+2);
        COMPUTE_Q(Ah1,Bh1,Al1,Bl1);
        __syncthreads();
    }
#undef STAGE_Q
#undef COMPUTE_Q

    // ---------- epilogue: per-wave LDS transpose -> contiguous row stores ----
    unsigned short* scrH = (w==0)?Ah0:(w==1)?Ah1:(w==2)?Bh0:Bh1;
    unsigned short* scrL = (w==0)?Al0:(w==1)?Al1:(w==2)?Bl0:Bl1;
    const int cb  = n0 + wc*64;           // 64-aligned -> single (z,h), e0=0
    const int rem = cb & 1023;
    const int h   = rem >> 6;
    const int mw  = m0 + wr*64;
    const int b   = mw >> 11;
    const int t0  = mw & (T_-1);

    if (precise){
        const int z = cb >> 10;
        const float scl = (z==0) ? 8.0f : 1.0f;
        const float* bias = (z==0) ? bqv : bkv;
        unsigned short* oh = (z==0) ? qhp : khp;
        unsigned short* ol = (z==0) ? qlp : klp;
        float biasv[4];
#pragma unroll
        for (int nf=0;nf<4;nf++) biasv[nf] = bias[rem + nf*16 + fla];
        // write: row = t_loc = mf*16+flb*4+ri, col = e = nf*16+fla
#pragma unroll
        for (int mf=0; mf<4; ++mf)
#pragma unroll
            for (int nf=0; nf<4; ++nf)
#pragma unroll
                for (int ri=0; ri<4; ++ri){
                    const int row = mf*16 + flb*4 + ri;
                    const int col = nf*16 + fla;
                    const int a = row*64 + (((col>>3) ^ (row&7))<<3) + (col&7);
                    const float val = (acc[mf][nf][ri] + biasv[nf]) * scl;
                    const unsigned short hb = f2bf(val);
                    scrH[a] = hb;
                    scrL[a] = f2bf(val - bfbits2f(hb));
                }
        const size_t rowbase = ((size_t)(b*H_ + h)*T_ + t0 + lane)*HD_;
#pragma unroll
        for (int c=0;c<8;c++){
            const int pc = (c ^ (lane&7))<<3;
            *(uint4*)(oh + rowbase + c*8) = *(const uint4*)&scrH[lane*64 + pc];
            *(uint4*)(ol + rowbase + c*8) = *(const uint4*)&scrL[lane*64 + pc];
        }
    } else {
        float biasv[4];
#pragma unroll
        for (int nf=0;nf<4;nf++) biasv[nf] = bvv[rem + nf*16 + fla];
        // write transposed: row = e = nf*16+fla, col = t_loc = mf*16+flb*4+ri
#pragma unroll
        for (int mf=0; mf<4; ++mf)
#pragma unroll
            for (int nf=0; nf<4; ++nf)
#pragma unroll
                for (int ri=0; ri<4; ++ri){
                    const int row = nf*16 + fla;
                    const int col = mf*16 + flb*4 + ri;
                    const int a = row*64 + (((col>>3) ^ (row&7))<<3) + (col&7);
                    scrH[a] = f2bf(acc[mf][nf][ri] + biasv[nf]);
                }
        const size_t rowbase = ((size_t)((b*H_ + h)*HD_ + lane))*T_ + t0;
#pragma unroll
        for (int c=0;c<8;c++){
            const int pc = (c ^ (lane&7))<<3;
            *(uint4*)(vtp + rowbase + c*8) = *(const uint4*)&scrH[lane*64 + pc];
        }
    }
}

// ---------------------------------------------------------------------------
// gemm_o: out = att(bf16) @ wot(bf16) + bo. 2-phase double-buffered,
// gload_lds + chunk-XOR swizzle (same scheme as gemm_qkv3 hi path).
// ---------------------------------------------------------------------------
__global__ __launch_bounds__(256) void gemm_o(
    const unsigned short* __restrict__ attb, const unsigned short* __restrict__ wot,
    const float* __restrict__ bo, float* __restrict__ out)
{
    const int m0 = blockIdx.x * 128;
    const int n0 = blockIdx.y * 128;
    const int tid = threadIdx.x;
    const int lane = tid & 63, w = tid >> 6;
    const int wr = w >> 1, wc = w & 1;
    const int fla = lane & 15, flb = lane >> 4;

    __shared__ unsigned short Ao0[4096], Ao1[4096];
    __shared__ unsigned short Bo0[4096], Bo1[4096];

    f32x4 acc[4][4];
#pragma unroll
    for (int i=0;i<4;i++)
#pragma unroll
        for (int j=0;j<4;j++) acc[i][j] = (f32x4){0.f,0.f,0.f,0.f};

    const int srow0 = w*32 + (lane>>2);
    const int srow1 = srow0 + 16;
    const int spc   = lane & 3;
    const size_t ga0 = (size_t)(m0+srow0)*1024 + (size_t)((spc ^ ((srow0>>1)&3))*8);
    const size_t ga1 = (size_t)(m0+srow1)*1024 + (size_t)((spc ^ ((srow1>>1)&3))*8);
    const size_t gb0 = (size_t)(n0+srow0)*1024 + (size_t)((spc ^ ((srow0>>1)&3))*8);
    const size_t gb1 = (size_t)(n0+srow1)*1024 + (size_t)((spc ^ ((srow1>>1)&3))*8);
    const int ldso0 = w*1024;
    const int ldso1 = w*1024 + 512;
    const int pchunk = (flb ^ ((fla>>1)&3)) * 8;

#define STAGE_O(AB,BB,KS) do{ const size_t k0_ = (size_t)(KS)*32;                 \
    gload_lds16(attb + ga0 + k0_, (AB) + ldso0);                                  \
    gload_lds16(attb + ga1 + k0_, (AB) + ldso1);                                  \
    gload_lds16(wot  + gb0 + k0_, (BB) + ldso0);                                  \
    gload_lds16(wot  + gb1 + k0_, (BB) + ldso1); }while(0)

#define COMPUTE_O(AB,BB) do{                                                      \
    bf16x8 af[4], bfr[4];                                                         \
    _Pragma("unroll")                                                             \
    for (int mf=0; mf<4; ++mf)                                                    \
        af[mf] = *(const bf16x8*)&(AB)[(wr*64+mf*16+fla)*32 + pchunk];            \
    _Pragma("unroll")                                                             \
    for (int nf=0; nf<4; ++nf)                                                    \
        bfr[nf] = *(const bf16x8*)&(BB)[(wc*64+nf*16+fla)*32 + pchunk];           \
    _Pragma("unroll")                                                             \
    for (int mf=0; mf<4; ++mf)                                                    \
        _Pragma("unroll")                                                         \
        for (int nf=0; nf<4; ++nf)                                                \
            acc[mf][nf] = __builtin_amdgcn_mfma_f32_16x16x32_bf16(                \
                              af[mf], bfr[nf], acc[mf][nf], 0, 0, 0); }while(0)

    STAGE_O(Ao0,Bo0, 0);
    __syncthreads();
    for (int ks = 0; ks < 32; ks += 2){
        STAGE_O(Ao1,Bo1, ks+1);
        COMPUTE_O(Ao0,Bo0);
        __syncthreads();
        if (ks+2 < 32) STAGE_O(Ao0,Bo0, ks+2);
        COMPUTE_O(Ao1,Bo1);
        __syncthreads();
    }
#undef STAGE_O
#undef COMPUTE_O

#pragma unroll
    for (int nf=0; nf<4; ++nf){
        const int n = n0 + wc*64 + nf*16 + fla;
        const float bias = bo[n];
#pragma unroll
        for (int mf=0; mf<4; ++mf){
#pragma unroll
            for (int ri=0; ri<4; ++ri){
                const int m = m0 + wr*64 + mf*16 + flb*4 + ri;
                out[(size_t)m*D_ + n] = acc[mf][nf][ri] + bias;
            }
        }
    }
}

// ---------------------------------------------------------------------------
// MFMA flash attention. (unchanged from round 10)
// ---------------------------------------------------------------------------
__global__ __launch_bounds__(256) void attn_mfma(
    const unsigned short* __restrict__ qhp, const unsigned short* __restrict__ qlp,
    const unsigned short* __restrict__ khp, const unsigned short* __restrict__ klp,
    const unsigned short* __restrict__ vtp, unsigned short* __restrict__ attb,
    const int* __restrict__ maskp)
{
    const int bid = blockIdx.x;
    const int qb  = 31 - (bid >> 6);   // big blocks first
    const int bh  = bid & 63;
    const int b   = bh >> 4, h = bh & 15;
    const int tid = threadIdx.x;
    const int lane = tid & 63, w = tid >> 6;
    const int l16 = lane & 15, h16 = lane >> 4;
    const int domask = maskp[0];

    __shared__ unsigned short KhS[64][72];
    __shared__ unsigned short KlS[64][72];
    __shared__ unsigned short VtS[64][72];   // [d][key]
    __shared__ unsigned short PsS[64][72];   // wave-private rows

    const int qrow = qb*64 + w*16 + l16;
    const size_t qoff = ((size_t)bh*T_ + qrow)*HD_ + 8*h16;
    const bf16x8 qh0 = *(const bf16x8*)(qhp + qoff);
    const bf16x8 qh1 = *(const bf16x8*)(qhp + qoff + 32);
    const bf16x8 ql0 = *(const bf16x8*)(qlp + qoff);
    const bf16x8 ql1 = *(const bf16x8*)(qlp + qoff + 32);

    f32x4 accO[4];
#pragma unroll
    for (int j=0;j<4;j++) accO[j] = (f32x4){0.f,0.f,0.f,0.f};
    float m_run[4], l_run[4];
#pragma unroll
    for (int i=0;i<4;i++){ m_run[i] = -INFINITY; l_run[i] = 0.f; }

    const int r   = tid >> 2;         // staging row 0..63
    const int c16 = (tid & 3) * 16;   // staging col base
    const size_t kbase = (size_t)bh*T_*HD_;
    const size_t vbase = (size_t)bh*HD_*T_;

    const int kv_end = domask ? qb : 31;
    for (int kv = 0; kv <= kv_end; ++kv){
        const unsigned short* ksrc = khp + kbase + (size_t)(kv*64+r)*HD_ + c16;
        uint4 a0 = *(const uint4*)(ksrc);
        uint4 a1 = *(const uint4*)(ksrc+8);
        const unsigned short* lsrc = klp + kbase + (size_t)(kv*64+r)*HD_ + c16;
        uint4 a2 = *(const uint4*)(lsrc);
        uint4 a3 = *(const uint4*)(lsrc+8);
        const unsigned short* vsrc = vtp + vbase + (size_t)r*T_ + kv*64 + c16;
        uint4 a4 = *(const uint4*)(vsrc);
        uint4 a5 = *(const uint4*)(vsrc+8);
        __syncthreads();   // prev tile reads done
        *(uint4*)&KhS[r][c16] = a0; *(uint4*)&KhS[r][c16+8] = a1;
        *(uint4*)&KlS[r][c16] = a2; *(uint4*)&KlS[r][c16+8] = a3;
        *(uint4*)&VtS[r][c16] = a4; *(uint4*)&VtS[r][c16+8] = a5;
        __syncthreads();

        // S = Q K^T  (split precision, small terms first)
        f32x4 s[4];
#pragma unroll
        for (int j=0;j<4;j++){
            const bf16x8 kh0 = *(const bf16x8*)&KhS[j*16+l16][8*h16];
            const bf16x8 kh1 = *(const bf16x8*)&KhS[j*16+l16][32+8*h16];
            const bf16x8 kl0 = *(const bf16x8*)&KlS[j*16+l16][8*h16];
            const bf16x8 kl1 = *(const bf16x8*)&KlS[j*16+l16][32+8*h16];
            f32x4 a = (f32x4){0.f,0.f,0.f,0.f};
            a = __builtin_amdgcn_mfma_f32_16x16x32_bf16(qh0, kl0, a, 0,0,0);
            a = __builtin_amdgcn_mfma_f32_16x16x32_bf16(ql0, kh0, a, 0,0,0);
            a = __builtin_amdgcn_mfma_f32_16x16x32_bf16(qh1, kl1, a, 0,0,0);
            a = __builtin_amdgcn_mfma_f32_16x16x32_bf16(ql1, kh1, a, 0,0,0);
            a = __builtin_amdgcn_mfma_f32_16x16x32_bf16(qh0, kh0, a, 0,0,0);
            a = __builtin_amdgcn_mfma_f32_16x16x32_bf16(qh1, kh1, a, 0,0,0);
            s[j] = a;
        }
        if (domask && kv == qb){
#pragma unroll
            for (int j=0;j<4;j++)
#pragma unroll
                for (int reg=0;reg<4;reg++)
                    if (j*16+l16 > w*16 + h16*4 + reg) s[j][reg] = -INFINITY;
        }

        // online softmax; rows = w*16 + h16*4 + reg
#pragma unroll
        for (int reg=0; reg<4; ++reg){
            float mloc = fmaxf(fmaxf(s[0][reg],s[1][reg]), fmaxf(s[2][reg],s[3][reg]));
            mloc = fmaxf(mloc, __shfl_xor(mloc,1));
            mloc = fmaxf(mloc, __shfl_xor(mloc,2));
            mloc = fmaxf(mloc, __shfl_xor(mloc,4));
            mloc = fmaxf(mloc, __shfl_xor(mloc,8));
            float mnew = fmaxf(m_run[reg], mloc);
            float scl  = __expf(m_run[reg] - mnew);   // exp(-inf)=0 first tile
            m_run[reg] = mnew;
            float p0 = __expf(s[0][reg]-mnew);
            float p1 = __expf(s[1][reg]-mnew);
            float p2 = __expf(s[2][reg]-mnew);
            float p3 = __expf(s[3][reg]-mnew);
            float rs = p0+p1+p2+p3;
            rs += __shfl_xor(rs,1); rs += __shfl_xor(rs,2);
            rs += __shfl_xor(rs,4); rs += __shfl_xor(rs,8);
            l_run[reg] = l_run[reg]*scl + rs;
            accO[0][reg] *= scl; accO[1][reg] *= scl;
            accO[2][reg] *= scl; accO[3][reg] *= scl;
            const int prow = w*16 + h16*4 + reg;
            PsS[prow][ 0+l16] = f2bf(p0);
            PsS[prow][16+l16] = f2bf(p1);
            PsS[prow][32+l16] = f2bf(p2);
            PsS[prow][48+l16] = f2bf(p3);
        }

        // O += P V  (PsS rows wave-private)
#pragma unroll
        for (int c=0;c<2;c++){
            const bf16x8 pa = *(const bf16x8*)&PsS[w*16+l16][c*32+8*h16];
#pragma unroll
            for (int j=0;j<4;j++){
                const bf16x8 vb_ = *(const bf16x8*)&VtS[j*16+l16][c*32+8*h16];
                accO[j] = __builtin_amdgcn_mfma_f32_16x16x32_bf16(pa, vb_, accO[j], 0,0,0);
            }
        }
    }

#pragma unroll
    for (int reg=0;reg<4;reg++){
        const float inv = 1.0f / l_run[reg];
        const int t = qb*64 + w*16 + h16*4 + reg;
#pragma unroll
        for (int j=0;j<4;j++){
            attb[((size_t)b*T_ + t)*D_ + h*HD_ + j*16 + l16] =
                f2bf(accO[j][reg]*inv);
        }
    }
}

extern "C" void kernel_launch(void* const* d_in, const int* in_sizes, int n_in,
                              void* d_out, int out_size, void* d_ws, size_t ws_size,
                              hipStream_t stream)
{
    const float* x  = (const float*)d_in[0];
    const float* Wq = (const float*)d_in[1];
    const float* bq = (const float*)d_in[2];
    const float* Wk = (const float*)d_in[3];
    const float* bk = (const float*)d_in[4];
    const float* Wv = (const float*)d_in[5];
    const float* bv = (const float*)d_in[6];
    const float* Wo = (const float*)d_in[7];
    const float* bo = (const float*)d_in[8];
    const int* mask = (const int*)d_in[9];
    float* out = (float*)d_out;

    // workspace (126 MiB): all bf16
    unsigned short* qhp = (unsigned short*)d_ws;                 // 16 MiB
    unsigned short* qlp = qhp + (size_t)8*1024*1024;             // 16 MiB
    unsigned short* khp = qlp + (size_t)8*1024*1024;             // 16 MiB
    unsigned short* klp = khp + (size_t)8*1024*1024;             // 16 MiB
    unsigned short* vtp = klp + (size_t)8*1024*1024;             // 16 MiB [bh][d][t]
    unsigned short* xh  = vtp + (size_t)8*1024*1024;             // 16 MiB
    unsigned short* xl  = xh  + (size_t)8*1024*1024;             // 16 MiB
    unsigned short* wh  = xl  + (size_t)8*1024*1024;             // 6 MiB
    unsigned short* wl  = wh  + (size_t)3*1024*1024;             // 6 MiB
    unsigned short* wot = wl  + (size_t)3*1024*1024;             // 2 MiB
    unsigned short* attb = xh;   // alias: xh dead after gemm_qkv3

    prep_x2   <<<2048, 256, 0, stream>>>(x, xh, xl);
    prep_wqkv2<<<dim3(16,48), 256, 0, stream>>>(Wq, Wk, Wv, wh, wl);
    prep_wo   <<<dim3(16,16), 256, 0, stream>>>(Wo, wot);
    gemm_qkv3 <<<dim3(64,24), 256, 0, stream>>>(xh, xl, wh, wl, bq, bk, bv,
                                                qhp, qlp, khp, klp, vtp);
    attn_mfma <<<2048, 256, 0, stream>>>(qhp, qlp, khp, klp, vtp, attb, mask);
    gemm_o    <<<dim3(64,8), 256, 0, stream>>>(attb, wot, bo, out);
}